// Round 7
// baseline (157.020 us; speedup 1.0000x reference)
//
#include <hip/hip_runtime.h>
#include <hip/hip_bf16.h>

#define NB 2
#define SEQ 4096
#define DM 512
#define NH 8
#define DKH 64
#define MTOT (NB*SEQ)   // 8192

typedef __attribute__((ext_vector_type(4))) float f32x4;
typedef __attribute__((ext_vector_type(16))) float f32x16;
typedef __attribute__((ext_vector_type(8))) short bf16x8;
typedef __attribute__((ext_vector_type(2))) unsigned uint2v;

__device__ inline unsigned short f2bf(float f) {
    union { float f; unsigned int u; } v; v.f = f;
    unsigned int r = v.u + 0x7FFFu + ((v.u >> 16) & 1u);
    return (unsigned short)(r >> 16);
}

// Q prescale: 1/sqrt(d_k) * log2(e) so softmax runs in exp2 domain
#define QSCALE 0.18033688011112042f

// ---------------- cast fp32 -> bf16 for x, Wq, Wk, Wv, Wo ----------------
__global__ void cast_kernel(const float* __restrict__ x, const float* __restrict__ wq,
                            const float* __restrict__ wk, const float* __restrict__ wv,
                            const float* __restrict__ wo, unsigned short* __restrict__ dst) {
    const int NX = MTOT*DM;      // 4194304
    const int NW = DM*DM;        // 262144
    int i4 = blockIdx.x * blockDim.x + threadIdx.x;
    long e = (long)i4 * 4;
    if (e >= NX + 4L*NW) return;
    const float* src; long off;
    if (e < NX)           { src = x;  off = e; }
    else if (e < NX+NW)   { src = wq; off = e - NX; }
    else if (e < NX+2*NW) { src = wk; off = e - NX - NW; }
    else if (e < NX+3*NW) { src = wv; off = e - NX - 2*NW; }
    else                  { src = wo; off = e - NX - 3*NW; }
    float4 v = *reinterpret_cast<const float4*>(src + off);
    ushort4 o;
    o.x = f2bf(v.x); o.y = f2bf(v.y); o.z = f2bf(v.z); o.w = f2bf(v.w);
    *reinterpret_cast<ushort4*>(dst + e) = o;
}

// ---------------- B^T GEMM: C[M][N] = A[M][K] * B[N][K]^T ----------------
template<int MODE>
__global__ __launch_bounds__(256, 2) void gemm_bt(
    const unsigned short* __restrict__ A,
    const unsigned short* __restrict__ B,
    const float* __restrict__ bias,      // MODE0: b_v, MODE1: b_o
    unsigned short* __restrict__ Qh, unsigned short* __restrict__ Kh,
    unsigned short* __restrict__ Vt,
    float* __restrict__ Cout)
{
    const int K = 512;
    __shared__ __align__(16) unsigned short As[128*64];
    __shared__ __align__(16) unsigned short Bs[128*64];
    int tid = threadIdx.x;
    int wid = tid >> 6, lane = tid & 63;
    int wr = wid >> 1, wc = wid & 1;
    int brow = blockIdx.x * 128;
    int bcol = blockIdx.y * 128;
    int l15 = lane & 15, l4 = lane >> 4;

    f32x4 acc[4][4] = {};

    for (int kt = 0; kt < K/64; ++kt) {
        __syncthreads();
        // global -> LDS direct (linear dest, inverse-swizzled per-lane source)
        #pragma unroll
        for (int i = 0; i < 4; ++i) {
            int rbase = i*32 + wid*8;
            int row = rbase + (lane >> 3);
            int csrc = (lane & 7) ^ (row & 7);
            const unsigned short* asrc = A + (long)(brow+row)*K + kt*64 + csrc*8;
            __builtin_amdgcn_global_load_lds(
                (const __attribute__((address_space(1))) unsigned int*)asrc,
                (__attribute__((address_space(3))) unsigned int*)&As[rbase*64], 16, 0, 0);
            const unsigned short* bsrc = B + (long)(bcol+row)*K + kt*64 + csrc*8;
            __builtin_amdgcn_global_load_lds(
                (const __attribute__((address_space(1))) unsigned int*)bsrc,
                (__attribute__((address_space(3))) unsigned int*)&Bs[rbase*64], 16, 0, 0);
        }
        __syncthreads();
        #pragma unroll
        for (int kk = 0; kk < 2; ++kk) {
            bf16x8 af[4], bfr[4];
            #pragma unroll
            for (int mi = 0; mi < 4; ++mi) {
                int row = wr*64 + mi*16 + l15;
                int colb = (kk*32 + l4*8) * 2;
                af[mi] = *reinterpret_cast<const bf16x8*>(
                    reinterpret_cast<const char*>(As) + row*128 + (colb ^ ((row&7)<<4)));
            }
            #pragma unroll
            for (int ni = 0; ni < 4; ++ni) {
                int row = wc*64 + ni*16 + l15;
                int colb = (kk*32 + l4*8) * 2;
                bfr[ni] = *reinterpret_cast<const bf16x8*>(
                    reinterpret_cast<const char*>(Bs) + row*128 + (colb ^ ((row&7)<<4)));
            }
            #pragma unroll
            for (int mi = 0; mi < 4; ++mi)
                #pragma unroll
                for (int ni = 0; ni < 4; ++ni)
                    acc[mi][ni] = __builtin_amdgcn_mfma_f32_16x16x32_bf16(af[mi], bfr[ni], acc[mi][ni], 0, 0, 0);
        }
    }

    #pragma unroll
    for (int mi = 0; mi < 4; ++mi) {
        #pragma unroll
        for (int ni = 0; ni < 4; ++ni) {
            #pragma unroll
            for (int r = 0; r < 4; ++r) {
                int row = brow + wr*64 + mi*16 + l4*4 + r;
                int col = bcol + wc*64 + ni*16 + l15;
                float v = acc[mi][ni][r];
                if (MODE == 0) {
                    int which = col >> 9;
                    int cw = col & 511;
                    int h = cw >> 6, d = cw & 63;
                    int b = row >> 12, s = row & 4095;
                    int bh = b*NH + h;
                    if (which == 0) {
                        Qh[((long)(bh*SEQ + s))*DKH + d] = f2bf(v * QSCALE);
                    } else if (which == 1) {
                        Kh[((long)(bh*SEQ + s))*DKH + d] = f2bf(v);
                    } else {
                        Vt[((long)(bh*DKH + d))*SEQ + s] = f2bf(v + bias[cw]);
                    }
                } else {
                    Cout[(long)row*DM + col] = v + bias[col];
                }
            }
        }
    }
}

// ---------------- causal flash attention: 32x32 swapped, KVBLK=128 ----------
// 2-deep score pipeline: STEP(kb) issues QK(kb+1) MFMAs first, then runs
// softmax(kb) on the VALU while they drain, then PV(kb). K prefetch distance 2.
// grid (16 bh, 32 ty); block 256 = 4 waves; wave owns 32 q-rows (tile = 128).
__global__ __launch_bounds__(256, 2) void attn_kernel(
    const unsigned short* __restrict__ Qh,
    const unsigned short* __restrict__ Kh,
    const unsigned short* __restrict__ Vt,
    unsigned short* __restrict__ Obf)
{
    __shared__ __align__(16) unsigned short Klds[2][128*64];   // [key][d] 128B rows
    __shared__ __align__(16) unsigned short Vlds[2][2*64*64];  // two [d][64key] sub-tiles
    const int tid = threadIdx.x;
    const int wid = tid >> 6, lane = tid & 63;
    const int l31 = lane & 31;
    const int hi  = lane >> 5;
    const int bh  = blockIdx.x;
    const int ty  = blockIdx.y;
    const int tile = ty < 16 ? 31 - ty : ty - 16;   // dispatch-order pairing

    const unsigned short* Qbase = Qh + (long)bh*SEQ*DKH;
    const unsigned short* Kbase = Kh + (long)bh*SEQ*DKH;
    const unsigned short* Vbase = Vt + (long)bh*DKH*SEQ;

    const int q0w = tile*128 + wid*32;
    const int q   = q0w + l31;
    const int nt  = tile + 1;          // 128-key blocks
    const int swz = (l31 & 7) << 4;

    // Q as B-operand frags: qf[kk][e] = Q[q][kk*16 + hi*8 + e]
    bf16x8 qf[4];
    #pragma unroll
    for (int kk = 0; kk < 4; ++kk)
        qf[kk] = *reinterpret_cast<const bf16x8*>(Qbase + (long)q*DKH + kk*16 + hi*8);

    auto STAGE_K = [&](int b, int key0) {
        #pragma unroll
        for (int ii = 0; ii < 4; ++ii) {
            const int rbase = wid*32 + ii*8;
            const int row = rbase + (lane >> 3);
            const int ck = (lane & 7) ^ (row & 7);
            const unsigned short* ksrc = Kbase + (long)(key0 + row)*DKH + ck*8;
            __builtin_amdgcn_global_load_lds(
                (const __attribute__((address_space(1))) unsigned int*)ksrc,
                (__attribute__((address_space(3))) unsigned int*)&Klds[b][rbase*64], 16, 0, 0);
        }
    };
    auto STAGE_V = [&](int b, int key0) {
        #pragma unroll
        for (int jj = 0; jj < 2; ++jj) {
            #pragma unroll
            for (int ii = 0; ii < 2; ++ii) {
                const int rbase = wid*16 + ii*8;
                const int row = rbase + (lane >> 3);
                const int ck = (lane & 7) ^ (row & 7);
                const unsigned short* vsrc = Vbase + (long)row*SEQ + key0 + jj*64 + ck*8;
                __builtin_amdgcn_global_load_lds(
                    (const __attribute__((address_space(1))) unsigned int*)vsrc,
                    (__attribute__((address_space(3))) unsigned int*)&Vlds[b][jj*4096 + rbase*64], 16, 0, 0);
            }
        }
    };

    float m = -1e30f, lsum = 0.f;
    f32x16 od0 = {}, od1 = {};

    // prologue: K(0), K(1), V(0); then QK(0) -> sA
    STAGE_K(0, 0);
    if (nt > 1) STAGE_K(1, 128);
    STAGE_V(0, 0);
    __syncthreads();

    f32x16 sA0 = {}, sA1 = {}, sA2 = {}, sA3 = {};
    {
        const char* kl = reinterpret_cast<const char*>(Klds[0]);
        __builtin_amdgcn_s_setprio(1);
        #pragma unroll
        for (int kk = 0; kk < 4; ++kk) {
            const int co = (kk*32 + hi*16) ^ swz;
            bf16x8 kf0 = *reinterpret_cast<const bf16x8*>(kl + l31*128       + co);
            sA0 = __builtin_amdgcn_mfma_f32_32x32x16_bf16(kf0, qf[kk], sA0, 0, 0, 0);
            bf16x8 kf1 = *reinterpret_cast<const bf16x8*>(kl + (32+l31)*128  + co);
            sA1 = __builtin_amdgcn_mfma_f32_32x32x16_bf16(kf1, qf[kk], sA1, 0, 0, 0);
            bf16x8 kf2 = *reinterpret_cast<const bf16x8*>(kl + (64+l31)*128  + co);
            sA2 = __builtin_amdgcn_mfma_f32_32x32x16_bf16(kf2, qf[kk], sA2, 0, 0, 0);
            bf16x8 kf3 = *reinterpret_cast<const bf16x8*>(kl + (96+l31)*128  + co);
            sA3 = __builtin_amdgcn_mfma_f32_32x32x16_bf16(kf3, qf[kk], sA3, 0, 0, 0);
        }
        __builtin_amdgcn_s_setprio(0);
    }
    __syncthreads();   // protect Klds[0] before STEP(0) stages K(2) into it

    f32x16 sB0, sB1, sB2, sB3;

#define EXP_CHUNK(SV, RS) do {                                                     \
        _Pragma("unroll")                                                          \
        for (int r = 0; r < 16; ++r) {                                             \
            SV[r] = __builtin_amdgcn_exp2f(SV[r] - m);                             \
            RS += SV[r];                                                           \
        } } while (0)

#define PV_STEP(SV, VLS, KS, B0) do {                                              \
        unsigned c0, c1, c2, c3;                                                   \
        float t0 = SV[B0+0], t1 = SV[B0+1], t2 = SV[B0+2], t3 = SV[B0+3];          \
        float t4 = SV[B0+4], t5 = SV[B0+5], t6 = SV[B0+6], t7 = SV[B0+7];          \
        asm("v_cvt_pk_bf16_f32 %0, %1, %2" : "=v"(c0) : "v"(t0), "v"(t1));         \
        asm("v_cvt_pk_bf16_f32 %0, %1, %2" : "=v"(c1) : "v"(t2), "v"(t3));         \
        asm("v_cvt_pk_bf16_f32 %0, %1, %2" : "=v"(c2) : "v"(t4), "v"(t5));         \
        asm("v_cvt_pk_bf16_f32 %0, %1, %2" : "=v"(c3) : "v"(t6), "v"(t7));         \
        uint2v sw0 = __builtin_amdgcn_permlane32_swap(c0, c2, false, false);       \
        uint2v sw1 = __builtin_amdgcn_permlane32_swap(c1, c3, false, false);       \
        union { unsigned u[4]; bf16x8 v; } pu;                                     \
        pu.u[0] = sw0[0]; pu.u[1] = sw1[0]; pu.u[2] = sw0[1]; pu.u[3] = sw1[1];    \
        bf16x8 vf0 = *reinterpret_cast<const bf16x8*>(VLS + l31*128      + (((KS)*32 + hi*16) ^ swz)); \
        od0 = __builtin_amdgcn_mfma_f32_32x32x16_bf16(vf0, pu.v, od0, 0, 0, 0);    \
        bf16x8 vf1 = *reinterpret_cast<const bf16x8*>(VLS + (32+l31)*128 + (((KS)*32 + hi*16) ^ swz)); \
        od1 = __builtin_amdgcn_mfma_f32_32x32x16_bf16(vf1, pu.v, od1, 0, 0, 0);    \
    } while (0)

#define STEP(C0, C1, C2, C3, X0, X1, X2, X3) do {                                  \
        const int key0 = kb << 7;                                                  \
        const bool hasN = (kb + 1 < nt);                                           \
        if (kb + 2 < nt) STAGE_K(kb & 1, (kb + 2) << 7);                           \
        if (hasN)        STAGE_V((kb + 1) & 1, (kb + 1) << 7);                     \
        /* QK(kb+1): issue MFMAs first so softmax VALU overlaps them */            \
        if (hasN) {                                                                \
            const char* klN = reinterpret_cast<const char*>(Klds[(kb + 1) & 1]);   \
            X0 = (f32x16){}; X1 = (f32x16){}; X2 = (f32x16){}; X3 = (f32x16){};    \
            __builtin_amdgcn_s_setprio(1);                                         \
            _Pragma("unroll")                                                      \
            for (int kk = 0; kk < 4; ++kk) {                                       \
                const int co = (kk*32 + hi*16) ^ swz;                              \
                bf16x8 kf0 = *reinterpret_cast<const bf16x8*>(klN + l31*128      + co); \
                X0 = __builtin_amdgcn_mfma_f32_32x32x16_bf16(kf0, qf[kk], X0, 0, 0, 0); \
                bf16x8 kf1 = *reinterpret_cast<const bf16x8*>(klN + (32+l31)*128 + co); \
                X1 = __builtin_amdgcn_mfma_f32_32x32x16_bf16(kf1, qf[kk], X1, 0, 0, 0); \
                bf16x8 kf2 = *reinterpret_cast<const bf16x8*>(klN + (64+l31)*128 + co); \
                X2 = __builtin_amdgcn_mfma_f32_32x32x16_bf16(kf2, qf[kk], X2, 0, 0, 0); \
                bf16x8 kf3 = *reinterpret_cast<const bf16x8*>(klN + (96+l31)*128 + co); \
                X3 = __builtin_amdgcn_mfma_f32_32x32x16_bf16(kf3, qf[kk], X3, 0, 0, 0); \
            }                                                                      \
            __builtin_amdgcn_s_setprio(0);                                         \
        }                                                                          \
        /* causal mask on current (diagonal block only) */                         \
        if (key0 + 127 > q0w) {                                                    \
            _Pragma("unroll")                                                      \
            for (int r = 0; r < 16; ++r) {                                         \
                const int ko = (r&3) + 8*(r>>2) + 4*hi;                            \
                if (key0 + ko > q)      C0[r] = -1e30f;                            \
                if (key0 + 32 + ko > q) C1[r] = -1e30f;                            \
                if (key0 + 64 + ko > q) C2[r] = -1e30f;                            \
                if (key0 + 96 + ko > q) C3[r] = -1e30f;                            \
            }                                                                      \
        }                                                                          \
        /* row max + partner exchange */                                           \
        float pmax = C0[0];                                                        \
        _Pragma("unroll")                                                          \
        for (int r = 1; r < 16; ++r) pmax = fmaxf(pmax, C0[r]);                    \
        _Pragma("unroll")                                                          \
        for (int r = 0; r < 16; ++r) pmax = fmaxf(pmax, fmaxf(C1[r], fmaxf(C2[r], C3[r]))); \
        {                                                                          \
            uint2v pr = __builtin_amdgcn_permlane32_swap(__float_as_uint(pmax), __float_as_uint(pmax), false, false); \
            pmax = fmaxf(__uint_as_float(pr[0]), __uint_as_float(pr[1]));          \
        }                                                                          \
        /* defer-max (T13) */                                                      \
        if (__any(pmax > m + 6.0f)) {                                              \
            const float mn = fmaxf(m, pmax);                                       \
            const float alpha = __builtin_amdgcn_exp2f(m - mn);                    \
            m = mn;                                                                \
            lsum *= alpha;                                                         \
            _Pragma("unroll")                                                      \
            for (int r = 0; r < 16; ++r) { od0[r] *= alpha; od1[r] *= alpha; }     \
        }                                                                          \
        /* exp + PV, chunk-interleaved */                                          \
        {                                                                          \
            const char* vl0 = reinterpret_cast<const char*>(Vlds[kb & 1]);         \
            const char* vl1 = vl0 + 8192;                                          \
            float rsc0 = 0.f, rsc1 = 0.f, rsc2 = 0.f, rsc3 = 0.f;                  \
            __builtin_amdgcn_s_setprio(1);                                         \
            EXP_CHUNK(C0, rsc0);                                                   \
            PV_STEP(C0, vl0, 0, 0);                                                \
            PV_STEP(C0, vl0, 1, 8);                                                \
            EXP_CHUNK(C1, rsc1);                                                   \
            PV_STEP(C1, vl0, 2, 0);                                                \
            PV_STEP(C1, vl0, 3, 8);                                                \
            EXP_CHUNK(C2, rsc2);                                                   \
            PV_STEP(C2, vl1, 0, 0);                                                \
            PV_STEP(C2, vl1, 1, 8);                                                \
            EXP_CHUNK(C3, rsc3);                                                   \
            PV_STEP(C3, vl1, 2, 0);                                                \
            PV_STEP(C3, vl1, 3, 8);                                                \
            __builtin_amdgcn_s_setprio(0);                                         \
            lsum += (rsc0 + rsc1) + (rsc2 + rsc3);                                 \
        }                                                                          \
        __syncthreads();                                                           \
    } while (0)

    int kb = 0;
    for (;;) {
        STEP(sA0, sA1, sA2, sA3, sB0, sB1, sB2, sB3);
        if (++kb >= nt) break;
        STEP(sB0, sB1, sB2, sB3, sA0, sA1, sA2, sA3);
        if (++kb >= nt) break;
    }
#undef STEP
#undef PV_STEP
#undef EXP_CHUNK

    // combine partner lsum, normalize, write O
    {
        uint2v pr = __builtin_amdgcn_permlane32_swap(__float_as_uint(lsum), __float_as_uint(lsum), false, false);
        lsum = __uint_as_float(pr[0]) + __uint_as_float(pr[1]);
    }
    const float rls = 1.0f / lsum;
    const long obase = (long)((bh >> 3)*SEQ + q)*DM + (bh & 7)*DKH;
    #pragma unroll
    for (int rr = 0; rr < 4; ++rr) {
        ushort4 w0, w1;
        w0.x = f2bf(od0[rr*4+0]*rls); w0.y = f2bf(od0[rr*4+1]*rls);
        w0.z = f2bf(od0[rr*4+2]*rls); w0.w = f2bf(od0[rr*4+3]*rls);
        *reinterpret_cast<ushort4*>(Obf + obase + rr*8 + hi*4) = w0;
        w1.x = f2bf(od1[rr*4+0]*rls); w1.y = f2bf(od1[rr*4+1]*rls);
        w1.z = f2bf(od1[rr*4+2]*rls); w1.w = f2bf(od1[rr*4+3]*rls);
        *reinterpret_cast<ushort4*>(Obf + obase + 32 + rr*8 + hi*4) = w1;
    }
}

extern "C" void kernel_launch(void* const* d_in, const int* in_sizes, int n_in,
                              void* d_out, int out_size, void* d_ws, size_t ws_size,
                              hipStream_t stream) {
    const float* x  = (const float*)d_in[0];
    const float* wq = (const float*)d_in[1];
    const float* wk = (const float*)d_in[2];
    const float* wv = (const float*)d_in[3];
    const float* bv = (const float*)d_in[4];
    const float* wo = (const float*)d_in[5];
    const float* bo = (const float*)d_in[6];
    float* out = (float*)d_out;

    unsigned short* ws = (unsigned short*)d_ws;
    unsigned short* Xbf  = ws;                       // 8192*512
    unsigned short* Wqkv = Xbf  + 4194304;           // 1536*512
    unsigned short* Wob  = Wqkv + 786432;            // 512*512
    unsigned short* Qh   = Wob  + 262144;            // [16][4096][64]
    unsigned short* Kh   = Qh   + 4194304;           // [16][4096][64]
    unsigned short* Vt   = Kh   + 4194304;           // [16][64][4096]
    unsigned short* Obf  = Vt   + 4194304;           // [8192][512]

    cast_kernel<<<5120, 256, 0, stream>>>(x, wq, wk, wv, wo, Xbf);

    dim3 g1(64, 12);
    gemm_bt<0><<<g1, 256, 0, stream>>>(Xbf, Wqkv, bv, Qh, Kh, Vt, nullptr);

    dim3 g2(16, 32);
    attn_kernel<<<g2, 256, 0, stream>>>(Qh, Kh, Vt, Obf);

    dim3 g3(64, 4);
    gemm_bt<1><<<g3, 256, 0, stream>>>(Obf, Wob, bo, nullptr, nullptr, nullptr, out);
}

// Round 8
// 128.406 us; speedup vs baseline: 1.2228x; 1.2228x over previous
//
#include <hip/hip_runtime.h>
#include <hip/hip_bf16.h>

#define NB 2
#define SEQ 4096
#define DM 512
#define NH 8
#define DKH 64
#define MTOT (NB*SEQ)   // 8192

typedef __attribute__((ext_vector_type(4))) float f32x4;
typedef __attribute__((ext_vector_type(16))) float f32x16;
typedef __attribute__((ext_vector_type(8))) short bf16x8;
typedef __attribute__((ext_vector_type(2))) unsigned uint2v;

__device__ inline unsigned short f2bf(float f) {
    union { float f; unsigned int u; } v; v.f = f;
    unsigned int r = v.u + 0x7FFFu + ((v.u >> 16) & 1u);
    return (unsigned short)(r >> 16);
}

// Q prescale: 1/sqrt(d_k) * log2(e) so softmax runs in exp2 domain
#define QSCALE 0.18033688011112042f

// ---------------- cast fp32 -> bf16 for x, Wq, Wk, Wv, Wo ----------------
__global__ void cast_kernel(const float* __restrict__ x, const float* __restrict__ wq,
                            const float* __restrict__ wk, const float* __restrict__ wv,
                            const float* __restrict__ wo, unsigned short* __restrict__ dst) {
    const int NX = MTOT*DM;      // 4194304
    const int NW = DM*DM;        // 262144
    int i4 = blockIdx.x * blockDim.x + threadIdx.x;
    long e = (long)i4 * 4;
    if (e >= NX + 4L*NW) return;
    const float* src; long off;
    if (e < NX)           { src = x;  off = e; }
    else if (e < NX+NW)   { src = wq; off = e - NX; }
    else if (e < NX+2*NW) { src = wk; off = e - NX - NW; }
    else if (e < NX+3*NW) { src = wv; off = e - NX - 2*NW; }
    else                  { src = wo; off = e - NX - 3*NW; }
    float4 v = *reinterpret_cast<const float4*>(src + off);
    ushort4 o;
    o.x = f2bf(v.x); o.y = f2bf(v.y); o.z = f2bf(v.z); o.w = f2bf(v.w);
    *reinterpret_cast<ushort4*>(dst + e) = o;
}

// ---------------- B^T GEMM: C[M][N] = A[M][K] * B[N][K]^T ----------------
template<int MODE>
__global__ __launch_bounds__(256, 2) void gemm_bt(
    const unsigned short* __restrict__ A,
    const unsigned short* __restrict__ B,
    const float* __restrict__ bias,      // MODE0: b_v, MODE1: b_o
    unsigned short* __restrict__ Qh, unsigned short* __restrict__ Kh,
    unsigned short* __restrict__ Vt,
    float* __restrict__ Cout)
{
    const int K = 512;
    __shared__ __align__(16) unsigned short As[128*64];
    __shared__ __align__(16) unsigned short Bs[128*64];
    int tid = threadIdx.x;
    int wid = tid >> 6, lane = tid & 63;
    int wr = wid >> 1, wc = wid & 1;
    int brow = blockIdx.x * 128;
    int bcol = blockIdx.y * 128;
    int l15 = lane & 15, l4 = lane >> 4;

    f32x4 acc[4][4] = {};

    for (int kt = 0; kt < K/64; ++kt) {
        __syncthreads();
        // global -> LDS direct (linear dest, inverse-swizzled per-lane source)
        #pragma unroll
        for (int i = 0; i < 4; ++i) {
            int rbase = i*32 + wid*8;
            int row = rbase + (lane >> 3);
            int csrc = (lane & 7) ^ (row & 7);
            const unsigned short* asrc = A + (long)(brow+row)*K + kt*64 + csrc*8;
            __builtin_amdgcn_global_load_lds(
                (const __attribute__((address_space(1))) unsigned int*)asrc,
                (__attribute__((address_space(3))) unsigned int*)&As[rbase*64], 16, 0, 0);
            const unsigned short* bsrc = B + (long)(bcol+row)*K + kt*64 + csrc*8;
            __builtin_amdgcn_global_load_lds(
                (const __attribute__((address_space(1))) unsigned int*)bsrc,
                (__attribute__((address_space(3))) unsigned int*)&Bs[rbase*64], 16, 0, 0);
        }
        __syncthreads();
        #pragma unroll
        for (int kk = 0; kk < 2; ++kk) {
            bf16x8 af[4], bfr[4];
            #pragma unroll
            for (int mi = 0; mi < 4; ++mi) {
                int row = wr*64 + mi*16 + l15;
                int colb = (kk*32 + l4*8) * 2;
                af[mi] = *reinterpret_cast<const bf16x8*>(
                    reinterpret_cast<const char*>(As) + row*128 + (colb ^ ((row&7)<<4)));
            }
            #pragma unroll
            for (int ni = 0; ni < 4; ++ni) {
                int row = wc*64 + ni*16 + l15;
                int colb = (kk*32 + l4*8) * 2;
                bfr[ni] = *reinterpret_cast<const bf16x8*>(
                    reinterpret_cast<const char*>(Bs) + row*128 + (colb ^ ((row&7)<<4)));
            }
            #pragma unroll
            for (int mi = 0; mi < 4; ++mi)
                #pragma unroll
                for (int ni = 0; ni < 4; ++ni)
                    acc[mi][ni] = __builtin_amdgcn_mfma_f32_16x16x32_bf16(af[mi], bfr[ni], acc[mi][ni], 0, 0, 0);
        }
    }

    #pragma unroll
    for (int mi = 0; mi < 4; ++mi) {
        #pragma unroll
        for (int ni = 0; ni < 4; ++ni) {
            #pragma unroll
            for (int r = 0; r < 4; ++r) {
                int row = brow + wr*64 + mi*16 + l4*4 + r;
                int col = bcol + wc*64 + ni*16 + l15;
                float v = acc[mi][ni][r];
                if (MODE == 0) {
                    int which = col >> 9;
                    int cw = col & 511;
                    int h = cw >> 6, d = cw & 63;
                    int b = row >> 12, s = row & 4095;
                    int bh = b*NH + h;
                    if (which == 0) {
                        Qh[((long)(bh*SEQ + s))*DKH + d] = f2bf(v * QSCALE);
                    } else if (which == 1) {
                        Kh[((long)(bh*SEQ + s))*DKH + d] = f2bf(v);
                    } else {
                        Vt[((long)(bh*DKH + d))*SEQ + s] = f2bf(v + bias[cw]);
                    }
                } else {
                    Cout[(long)row*DM + col] = v + bias[col];
                }
            }
        }
    }
}

// ---------------- causal flash attention: 32x32 swapped, KVBLK=128 ----------
// Uniform-work schedule: 128-thread blocks (2 waves x 32 q-rows = 64-row tile),
// each block processes tiles (63-ty) then (ty) sequentially -> exactly 33
// key-block units per block. 64KB LDS -> 2 blocks/CU, 4 waves/CU sustained.
__global__ __launch_bounds__(128, 1) void attn_kernel(
    const unsigned short* __restrict__ Qh,
    const unsigned short* __restrict__ Kh,
    const unsigned short* __restrict__ Vt,
    unsigned short* __restrict__ Obf)
{
    __shared__ __align__(16) unsigned short Klds[2][128*64];   // [key][d] 128B rows
    __shared__ __align__(16) unsigned short Vlds[2][2*64*64];  // two [d][64key] sub-tiles
    const int tid = threadIdx.x;
    const int wid = tid >> 6, lane = tid & 63;
    const int l31 = lane & 31;
    const int hi  = lane >> 5;
    const int bh  = blockIdx.x;
    const int ty  = blockIdx.y;          // 0..31

    const unsigned short* Qbase = Qh + (long)bh*SEQ*DKH;
    const unsigned short* Kbase = Kh + (long)bh*SEQ*DKH;
    const unsigned short* Vbase = Vt + (long)bh*DKH*SEQ;

    const int swz = (l31 & 7) << 4;

    auto STAGE_K = [&](int b, int key0) {
        #pragma unroll
        for (int ii = 0; ii < 8; ++ii) {
            const int rbase = wid*64 + ii*8;
            const int row = rbase + (lane >> 3);
            const int ck = (lane & 7) ^ (row & 7);
            const unsigned short* ksrc = Kbase + (long)(key0 + row)*DKH + ck*8;
            __builtin_amdgcn_global_load_lds(
                (const __attribute__((address_space(1))) unsigned int*)ksrc,
                (__attribute__((address_space(3))) unsigned int*)&Klds[b][rbase*64], 16, 0, 0);
        }
    };
    auto STAGE_V = [&](int b, int key0) {
        #pragma unroll
        for (int jj = 0; jj < 2; ++jj) {
            #pragma unroll
            for (int ii = 0; ii < 4; ++ii) {
                const int rbase = wid*32 + ii*8;
                const int row = rbase + (lane >> 3);
                const int ck = (lane & 7) ^ (row & 7);
                const unsigned short* vsrc = Vbase + (long)row*SEQ + key0 + jj*64 + ck*8;
                __builtin_amdgcn_global_load_lds(
                    (const __attribute__((address_space(1))) unsigned int*)vsrc,
                    (__attribute__((address_space(3))) unsigned int*)&Vlds[b][jj*4096 + rbase*64], 16, 0, 0);
            }
        }
    };

    #pragma unroll 1
    for (int half = 0; half < 2; ++half) {
        const int tile = half ? ty : 63 - ty;
        const int q0w = tile*64 + wid*32;
        const int q   = q0w + l31;
        const int nt  = (tile >> 1) + 1;     // 128-key blocks

        // Q as B-operand frags: qf[kk][e] = Q[q][kk*16 + hi*8 + e]
        bf16x8 qf[4];
        #pragma unroll
        for (int kk = 0; kk < 4; ++kk)
            qf[kk] = *reinterpret_cast<const bf16x8*>(Qbase + (long)q*DKH + kk*16 + hi*8);

        float m = -1e30f, lsum = 0.f;
        f32x16 od0 = {}, od1 = {};

        STAGE_K(0, 0);
        STAGE_V(0, 0);
        __syncthreads();
        int cur = 0;

        for (int kb = 0; kb < nt; ++kb) {
            if (kb + 1 < nt) { STAGE_K(cur ^ 1, (kb + 1) << 7); STAGE_V(cur ^ 1, (kb + 1) << 7); }
            const char* kl = reinterpret_cast<const char*>(Klds[cur]);
            const char* vl = reinterpret_cast<const char*>(Vlds[cur]);
            const int key0 = kb << 7;

            // hoist all 16 K-frag ds_reads ahead of the MFMA cluster
            bf16x8 kfr[4][4];
            #pragma unroll
            for (int kk = 0; kk < 4; ++kk) {
                const int co = (kk*32 + hi*16) ^ swz;
                #pragma unroll
                for (int c = 0; c < 4; ++c)
                    kfr[kk][c] = *reinterpret_cast<const bf16x8*>(kl + (c*32 + l31)*128 + co);
            }
            // QK^T (swapped): 4 independent chains, keys key0 + 32*c
            f32x16 s0 = {}, s1 = {}, s2 = {}, s3 = {};
            __builtin_amdgcn_s_setprio(1);
            #pragma unroll
            for (int kk = 0; kk < 4; ++kk) {
                s0 = __builtin_amdgcn_mfma_f32_32x32x16_bf16(kfr[kk][0], qf[kk], s0, 0, 0, 0);
                s1 = __builtin_amdgcn_mfma_f32_32x32x16_bf16(kfr[kk][1], qf[kk], s1, 0, 0, 0);
                s2 = __builtin_amdgcn_mfma_f32_32x32x16_bf16(kfr[kk][2], qf[kk], s2, 0, 0, 0);
                s3 = __builtin_amdgcn_mfma_f32_32x32x16_bf16(kfr[kk][3], qf[kk], s3, 0, 0, 0);
            }
            __builtin_amdgcn_s_setprio(0);

            // causal mask (diagonal block only): key of reg r = key0+32c+(r&3)+8*(r>>2)+4*hi
            if (key0 + 127 > q0w) {
                #pragma unroll
                for (int r = 0; r < 16; ++r) {
                    const int ko = (r&3) + 8*(r>>2) + 4*hi;
                    if (key0 + ko > q)      s0[r] = -1e30f;
                    if (key0 + 32 + ko > q) s1[r] = -1e30f;
                    if (key0 + 64 + ko > q) s2[r] = -1e30f;
                    if (key0 + 96 + ko > q) s3[r] = -1e30f;
                }
            }

            // row max: in-lane tree over 64 + partner exchange
            float pmax = s0[0];
            #pragma unroll
            for (int r = 1; r < 16; ++r) pmax = fmaxf(pmax, s0[r]);
            #pragma unroll
            for (int r = 0; r < 16; ++r) pmax = fmaxf(pmax, fmaxf(s1[r], fmaxf(s2[r], s3[r])));
            {
                uint2v pr = __builtin_amdgcn_permlane32_swap(__float_as_uint(pmax), __float_as_uint(pmax), false, false);
                pmax = fmaxf(__uint_as_float(pr[0]), __uint_as_float(pr[1]));
            }

            // defer-max (T13): rescale only when max grows past threshold
            if (__any(pmax > m + 6.0f)) {
                const float mn = fmaxf(m, pmax);
                const float alpha = __builtin_amdgcn_exp2f(m - mn);
                m = mn;
                lsum *= alpha;
                #pragma unroll
                for (int r = 0; r < 16; ++r) { od0[r] *= alpha; od1[r] *= alpha; }
            }

            float rsc0 = 0.f, rsc1 = 0.f, rsc2 = 0.f, rsc3 = 0.f;
#define EXP_CHUNK(SV, RS) do {                                                     \
            _Pragma("unroll")                                                      \
            for (int r = 0; r < 16; ++r) {                                         \
                SV[r] = __builtin_amdgcn_exp2f(SV[r] - m);                         \
                RS += SV[r];                                                       \
            } } while (0)

#define PV_STEP(SV, VLS, KS, B0) do {                                              \
            unsigned c0, c1, c2, c3;                                               \
            float t0 = SV[B0+0], t1 = SV[B0+1], t2 = SV[B0+2], t3 = SV[B0+3];      \
            float t4 = SV[B0+4], t5 = SV[B0+5], t6 = SV[B0+6], t7 = SV[B0+7];      \
            asm("v_cvt_pk_bf16_f32 %0, %1, %2" : "=v"(c0) : "v"(t0), "v"(t1));     \
            asm("v_cvt_pk_bf16_f32 %0, %1, %2" : "=v"(c1) : "v"(t2), "v"(t3));     \
            asm("v_cvt_pk_bf16_f32 %0, %1, %2" : "=v"(c2) : "v"(t4), "v"(t5));     \
            asm("v_cvt_pk_bf16_f32 %0, %1, %2" : "=v"(c3) : "v"(t6), "v"(t7));     \
            uint2v sw0 = __builtin_amdgcn_permlane32_swap(c0, c2, false, false);   \
            uint2v sw1 = __builtin_amdgcn_permlane32_swap(c1, c3, false, false);   \
            union { unsigned u[4]; bf16x8 v; } pu;                                 \
            pu.u[0] = sw0[0]; pu.u[1] = sw1[0]; pu.u[2] = sw0[1]; pu.u[3] = sw1[1];\
            bf16x8 vf0 = *reinterpret_cast<const bf16x8*>(VLS + l31*128      + (((KS)*32 + hi*16) ^ swz)); \
            od0 = __builtin_amdgcn_mfma_f32_32x32x16_bf16(vf0, pu.v, od0, 0, 0, 0);\
            bf16x8 vf1 = *reinterpret_cast<const bf16x8*>(VLS + (32+l31)*128 + (((KS)*32 + hi*16) ^ swz)); \
            od1 = __builtin_amdgcn_mfma_f32_32x32x16_bf16(vf1, pu.v, od1, 0, 0, 0);\
        } while (0)

            const char* vl0 = vl;          // keys key0 + 0..63
            const char* vl1 = vl + 8192;   // keys key0 + 64..127
            // chunk-interleaved: exp(c) VALU overlaps PV(c-1) MFMA drain
            EXP_CHUNK(s0, rsc0);
            PV_STEP(s0, vl0, 0, 0);
            PV_STEP(s0, vl0, 1, 8);
            EXP_CHUNK(s1, rsc1);
            PV_STEP(s1, vl0, 2, 0);
            PV_STEP(s1, vl0, 3, 8);
            EXP_CHUNK(s2, rsc2);
            PV_STEP(s2, vl1, 0, 0);
            PV_STEP(s2, vl1, 1, 8);
            EXP_CHUNK(s3, rsc3);
            PV_STEP(s3, vl1, 2, 0);
            PV_STEP(s3, vl1, 3, 8);
#undef PV_STEP
#undef EXP_CHUNK
            lsum += (rsc0 + rsc1) + (rsc2 + rsc3);

            __syncthreads();
            cur ^= 1;
        }

        // combine partner lsum, normalize, write O for this tile
        {
            uint2v pr = __builtin_amdgcn_permlane32_swap(__float_as_uint(lsum), __float_as_uint(lsum), false, false);
            lsum = __uint_as_float(pr[0]) + __uint_as_float(pr[1]);
        }
        const float rls = 1.0f / lsum;
        const long obase = (long)((bh >> 3)*SEQ + q)*DM + (bh & 7)*DKH;
        #pragma unroll
        for (int rr = 0; rr < 4; ++rr) {
            ushort4 w0, w1;
            w0.x = f2bf(od0[rr*4+0]*rls); w0.y = f2bf(od0[rr*4+1]*rls);
            w0.z = f2bf(od0[rr*4+2]*rls); w0.w = f2bf(od0[rr*4+3]*rls);
            *reinterpret_cast<ushort4*>(Obf + obase + rr*8 + hi*4) = w0;
            w1.x = f2bf(od1[rr*4+0]*rls); w1.y = f2bf(od1[rr*4+1]*rls);
            w1.z = f2bf(od1[rr*4+2]*rls); w1.w = f2bf(od1[rr*4+3]*rls);
            *reinterpret_cast<ushort4*>(Obf + obase + 32 + rr*8 + hi*4) = w1;
        }
    }
}

extern "C" void kernel_launch(void* const* d_in, const int* in_sizes, int n_in,
                              void* d_out, int out_size, void* d_ws, size_t ws_size,
                              hipStream_t stream) {
    const float* x  = (const float*)d_in[0];
    const float* wq = (const float*)d_in[1];
    const float* wk = (const float*)d_in[2];
    const float* wv = (const float*)d_in[3];
    const float* bv = (const float*)d_in[4];
    const float* wo = (const float*)d_in[5];
    const float* bo = (const float*)d_in[6];
    float* out = (float*)d_out;

    unsigned short* ws = (unsigned short*)d_ws;
    unsigned short* Xbf  = ws;                       // 8192*512
    unsigned short* Wqkv = Xbf  + 4194304;           // 1536*512
    unsigned short* Wob  = Wqkv + 786432;            // 512*512
    unsigned short* Qh   = Wob  + 262144;            // [16][4096][64]
    unsigned short* Kh   = Qh   + 4194304;           // [16][4096][64]
    unsigned short* Vt   = Kh   + 4194304;           // [16][64][4096]
    unsigned short* Obf  = Vt   + 4194304;           // [8192][512]

    cast_kernel<<<5120, 256, 0, stream>>>(x, wq, wk, wv, wo, Xbf);

    dim3 g1(64, 12);
    gemm_bt<0><<<g1, 256, 0, stream>>>(Xbf, Wqkv, bv, Qh, Kh, Vt, nullptr);

    dim3 g2(16, 32);
    attn_kernel<<<g2, 128, 0, stream>>>(Qh, Kh, Vt, Obf);

    dim3 g3(64, 4);
    gemm_bt<1><<<g3, 256, 0, stream>>>(Obf, Wob, bo, nullptr, nullptr, nullptr, out);
}

// Round 9
// 110.103 us; speedup vs baseline: 1.4261x; 1.1662x over previous
//
#include <hip/hip_runtime.h>
#include <hip/hip_bf16.h>

#define NB 2
#define SEQ 4096
#define DM 512
#define NH 8
#define DKH 64
#define MTOT (NB*SEQ)   // 8192

typedef __attribute__((ext_vector_type(4))) float f32x4;
typedef __attribute__((ext_vector_type(16))) float f32x16;
typedef __attribute__((ext_vector_type(8))) short bf16x8;
typedef __attribute__((ext_vector_type(2))) unsigned uint2v;

__device__ inline unsigned short f2bf(float f) {
    union { float f; unsigned int u; } v; v.f = f;
    unsigned int r = v.u + 0x7FFFu + ((v.u >> 16) & 1u);
    return (unsigned short)(r >> 16);
}

// Q prescale: 1/sqrt(d_k) * log2(e) so softmax runs in exp2 domain
#define QSCALE 0.18033688011112042f

// ---------------- cast fp32 -> bf16 for x, Wq, Wk, Wv, Wo ----------------
__global__ void cast_kernel(const float* __restrict__ x, const float* __restrict__ wq,
                            const float* __restrict__ wk, const float* __restrict__ wv,
                            const float* __restrict__ wo, unsigned short* __restrict__ dst) {
    const int NX = MTOT*DM;      // 4194304
    const int NW = DM*DM;        // 262144
    int i4 = blockIdx.x * blockDim.x + threadIdx.x;
    long e = (long)i4 * 4;
    if (e >= NX + 4L*NW) return;
    const float* src; long off;
    if (e < NX)           { src = x;  off = e; }
    else if (e < NX+NW)   { src = wq; off = e - NX; }
    else if (e < NX+2*NW) { src = wk; off = e - NX - NW; }
    else if (e < NX+3*NW) { src = wv; off = e - NX - 2*NW; }
    else                  { src = wo; off = e - NX - 3*NW; }
    float4 v = *reinterpret_cast<const float4*>(src + off);
    ushort4 o;
    o.x = f2bf(v.x); o.y = f2bf(v.y); o.z = f2bf(v.z); o.w = f2bf(v.w);
    *reinterpret_cast<ushort4*>(dst + e) = o;
}

// ---------------- B^T GEMM: C[M][N] = A[M][K] * B[N][K]^T ----------------
template<int MODE>
__global__ __launch_bounds__(256, 2) void gemm_bt(
    const unsigned short* __restrict__ A,
    const unsigned short* __restrict__ B,
    const float* __restrict__ bias,      // MODE0: b_v, MODE1: b_o
    unsigned short* __restrict__ Qh, unsigned short* __restrict__ Kh,
    unsigned short* __restrict__ Vt,
    float* __restrict__ Cout)
{
    const int K = 512;
    __shared__ __align__(16) unsigned short As[128*64];
    __shared__ __align__(16) unsigned short Bs[128*64];
    int tid = threadIdx.x;
    int wid = tid >> 6, lane = tid & 63;
    int wr = wid >> 1, wc = wid & 1;
    int brow = blockIdx.x * 128;
    int bcol = blockIdx.y * 128;
    int l15 = lane & 15, l4 = lane >> 4;

    f32x4 acc[4][4] = {};

    for (int kt = 0; kt < K/64; ++kt) {
        __syncthreads();
        // global -> LDS direct (linear dest, inverse-swizzled per-lane source)
        #pragma unroll
        for (int i = 0; i < 4; ++i) {
            int rbase = i*32 + wid*8;
            int row = rbase + (lane >> 3);
            int csrc = (lane & 7) ^ (row & 7);
            const unsigned short* asrc = A + (long)(brow+row)*K + kt*64 + csrc*8;
            __builtin_amdgcn_global_load_lds(
                (const __attribute__((address_space(1))) unsigned int*)asrc,
                (__attribute__((address_space(3))) unsigned int*)&As[rbase*64], 16, 0, 0);
            const unsigned short* bsrc = B + (long)(bcol+row)*K + kt*64 + csrc*8;
            __builtin_amdgcn_global_load_lds(
                (const __attribute__((address_space(1))) unsigned int*)bsrc,
                (__attribute__((address_space(3))) unsigned int*)&Bs[rbase*64], 16, 0, 0);
        }
        __syncthreads();
        #pragma unroll
        for (int kk = 0; kk < 2; ++kk) {
            bf16x8 af[4], bfr[4];
            #pragma unroll
            for (int mi = 0; mi < 4; ++mi) {
                int row = wr*64 + mi*16 + l15;
                int colb = (kk*32 + l4*8) * 2;
                af[mi] = *reinterpret_cast<const bf16x8*>(
                    reinterpret_cast<const char*>(As) + row*128 + (colb ^ ((row&7)<<4)));
            }
            #pragma unroll
            for (int ni = 0; ni < 4; ++ni) {
                int row = wc*64 + ni*16 + l15;
                int colb = (kk*32 + l4*8) * 2;
                bfr[ni] = *reinterpret_cast<const bf16x8*>(
                    reinterpret_cast<const char*>(Bs) + row*128 + (colb ^ ((row&7)<<4)));
            }
            #pragma unroll
            for (int mi = 0; mi < 4; ++mi)
                #pragma unroll
                for (int ni = 0; ni < 4; ++ni)
                    acc[mi][ni] = __builtin_amdgcn_mfma_f32_16x16x32_bf16(af[mi], bfr[ni], acc[mi][ni], 0, 0, 0);
        }
    }

    #pragma unroll
    for (int mi = 0; mi < 4; ++mi) {
        #pragma unroll
        for (int ni = 0; ni < 4; ++ni) {
            #pragma unroll
            for (int r = 0; r < 4; ++r) {
                int row = brow + wr*64 + mi*16 + l4*4 + r;
                int col = bcol + wc*64 + ni*16 + l15;
                float v = acc[mi][ni][r];
                if (MODE == 0) {
                    int which = col >> 9;
                    int cw = col & 511;
                    int h = cw >> 6, d = cw & 63;
                    int b = row >> 12, s = row & 4095;
                    int bh = b*NH + h;
                    if (which == 0) {
                        Qh[((long)(bh*SEQ + s))*DKH + d] = f2bf(v * QSCALE);
                    } else if (which == 1) {
                        Kh[((long)(bh*SEQ + s))*DKH + d] = f2bf(v);
                    } else {
                        Vt[((long)(bh*DKH + d))*SEQ + s] = f2bf(v + bias[cw]);
                    }
                } else {
                    Cout[(long)row*DM + col] = v + bias[col];
                }
            }
        }
    }
}

// ---------------- causal flash attention: split-K parity, uniform blocks ----
// Block = 256 thr = 4 waves: g=wid&1 row-group (32 rows), p=wid>>1 key-parity.
// 64-row tile; parity wave p handles key-blocks kb===p (mod 2) of 64 keys, with
// per-parity double-buffered LDS. Tiles (63-j) then (j) sequentially -> every
// block does exactly 33 supersteps; 512 blocks, 2/CU, 2 waves/SIMD sustained.
// Tile end: online-softmax merge of parity partials via LDS scratch.
__global__ __launch_bounds__(256, 2) void attn_kernel(
    const unsigned short* __restrict__ Qh,
    const unsigned short* __restrict__ Kh,
    const unsigned short* __restrict__ Vt,
    unsigned short* __restrict__ Obf)
{
    __shared__ __align__(16) unsigned short Klds[2][2][64*64];  // [parity][dbuf]
    __shared__ __align__(16) unsigned short Vlds[2][2][64*64];  // [parity][dbuf] [d][key]
    const int tid = threadIdx.x;
    const int wid = tid >> 6, lane = tid & 63;
    const int g = wid & 1, p = wid >> 1;
    const int l31 = lane & 31;
    const int hi  = lane >> 5;
    const int bh  = blockIdx.x;
    const int j   = blockIdx.y;          // 0..31

    const unsigned short* Qbase = Qh + (long)bh*SEQ*DKH;
    const unsigned short* Kbase = Kh + (long)bh*SEQ*DKH;
    const unsigned short* Vbase = Vt + (long)bh*DKH*SEQ;

    const int swz = (l31 & 7) << 4;

    // stage one 64-key K+V block for parity pb into dbuf b (all 4 waves share)
    auto STAGE1 = [&](int pb, int b, int key0) {
        #pragma unroll
        for (int ii = 0; ii < 2; ++ii) {
            const int rbase = wid*16 + ii*8;
            const int row = rbase + (lane >> 3);
            const int ck = (lane & 7) ^ (row & 7);
            const unsigned short* ksrc = Kbase + (long)(key0 + row)*DKH + ck*8;
            __builtin_amdgcn_global_load_lds(
                (const __attribute__((address_space(1))) unsigned int*)ksrc,
                (__attribute__((address_space(3))) unsigned int*)&Klds[pb][b][rbase*64], 16, 0, 0);
            const unsigned short* vsrc = Vbase + (long)row*SEQ + key0 + ck*8;
            __builtin_amdgcn_global_load_lds(
                (const __attribute__((address_space(1))) unsigned int*)vsrc,
                (__attribute__((address_space(3))) unsigned int*)&Vlds[pb][b][rbase*64], 16, 0, 0);
        }
    };

    #pragma unroll 1
    for (int half = 0; half < 2; ++half) {
        const int tile = half ? (int)j : 63 - (int)j;
        const int q0w = tile*64 + g*32;
        const int q   = q0w + l31;
        const int nss = (tile >> 1) + 1;

        bf16x8 qf[4];
        #pragma unroll
        for (int kk = 0; kk < 4; ++kk)
            qf[kk] = *reinterpret_cast<const bf16x8*>(Qbase + (long)q*DKH + kk*16 + hi*8);

        float m = -1e30f, lsum = 0.f;
        f32x16 od0 = {}, od1 = {};

        STAGE1(0, 0, 0);
        if (tile >= 1) STAGE1(1, 0, 64);
        __syncthreads();

        #pragma unroll 1
        for (int ss = 0; ss < nss; ++ss) {
            const int nb = (ss + 1) & 1;
            if (2*(ss+1)     <= tile) STAGE1(0, nb, (2*(ss+1))     << 6);
            if (2*(ss+1) + 1 <= tile) STAGE1(1, nb, (2*(ss+1) + 1) << 6);

            const int kb = 2*ss + p;           // wave-uniform
            if (kb <= tile) {
                const int key0 = kb << 6;
                const char* kl = reinterpret_cast<const char*>(&Klds[p][ss & 1][0]);
                const char* vl = reinterpret_cast<const char*>(&Vlds[p][ss & 1][0]);

                bf16x8 kfr[4][2];
                #pragma unroll
                for (int kk = 0; kk < 4; ++kk) {
                    const int co = (kk*32 + hi*16) ^ swz;
                    kfr[kk][0] = *reinterpret_cast<const bf16x8*>(kl + l31*128      + co);
                    kfr[kk][1] = *reinterpret_cast<const bf16x8*>(kl + (32+l31)*128 + co);
                }
                f32x16 s0 = {}, s1 = {};
                __builtin_amdgcn_s_setprio(1);
                #pragma unroll
                for (int kk = 0; kk < 4; ++kk) {
                    s0 = __builtin_amdgcn_mfma_f32_32x32x16_bf16(kfr[kk][0], qf[kk], s0, 0, 0, 0);
                    s1 = __builtin_amdgcn_mfma_f32_32x32x16_bf16(kfr[kk][1], qf[kk], s1, 0, 0, 0);
                }
                __builtin_amdgcn_s_setprio(0);

                if (kb == tile) {   // diagonal block
                    #pragma unroll
                    for (int r = 0; r < 16; ++r) {
                        const int ko = (r&3) + 8*(r>>2) + 4*hi;
                        if (key0 + ko > q)      s0[r] = -1e30f;
                        if (key0 + 32 + ko > q) s1[r] = -1e30f;
                    }
                }

                float pmax = s0[0];
                #pragma unroll
                for (int r = 1; r < 16; ++r) pmax = fmaxf(pmax, s0[r]);
                #pragma unroll
                for (int r = 0; r < 16; ++r) pmax = fmaxf(pmax, s1[r]);
                {
                    uint2v pr = __builtin_amdgcn_permlane32_swap(__float_as_uint(pmax), __float_as_uint(pmax), false, false);
                    pmax = fmaxf(__uint_as_float(pr[0]), __uint_as_float(pr[1]));
                }
                if (__any(pmax > m + 6.0f)) {
                    const float mn = fmaxf(m, pmax);
                    const float alpha = __builtin_amdgcn_exp2f(m - mn);
                    m = mn;
                    lsum *= alpha;
                    #pragma unroll
                    for (int r = 0; r < 16; ++r) { od0[r] *= alpha; od1[r] *= alpha; }
                }

                float rsc0 = 0.f, rsc1 = 0.f;
#define EXP_CHUNK(SV, RS) do {                                                     \
                _Pragma("unroll")                                                  \
                for (int r = 0; r < 16; ++r) {                                     \
                    SV[r] = __builtin_amdgcn_exp2f(SV[r] - m);                     \
                    RS += SV[r];                                                   \
                } } while (0)

#define PV_STEP(SV, VLS, KS, B0) do {                                              \
                unsigned c0, c1, c2, c3;                                           \
                float t0 = SV[B0+0], t1 = SV[B0+1], t2 = SV[B0+2], t3 = SV[B0+3];  \
                float t4 = SV[B0+4], t5 = SV[B0+5], t6 = SV[B0+6], t7 = SV[B0+7];  \
                asm("v_cvt_pk_bf16_f32 %0, %1, %2" : "=v"(c0) : "v"(t0), "v"(t1)); \
                asm("v_cvt_pk_bf16_f32 %0, %1, %2" : "=v"(c1) : "v"(t2), "v"(t3)); \
                asm("v_cvt_pk_bf16_f32 %0, %1, %2" : "=v"(c2) : "v"(t4), "v"(t5)); \
                asm("v_cvt_pk_bf16_f32 %0, %1, %2" : "=v"(c3) : "v"(t6), "v"(t7)); \
                uint2v sw0 = __builtin_amdgcn_permlane32_swap(c0, c2, false, false); \
                uint2v sw1 = __builtin_amdgcn_permlane32_swap(c1, c3, false, false); \
                union { unsigned u[4]; bf16x8 v; } pu;                             \
                pu.u[0] = sw0[0]; pu.u[1] = sw1[0]; pu.u[2] = sw0[1]; pu.u[3] = sw1[1]; \
                bf16x8 vf0 = *reinterpret_cast<const bf16x8*>(VLS + l31*128      + (((KS)*32 + hi*16) ^ swz)); \
                od0 = __builtin_amdgcn_mfma_f32_32x32x16_bf16(vf0, pu.v, od0, 0, 0, 0); \
                bf16x8 vf1 = *reinterpret_cast<const bf16x8*>(VLS + (32+l31)*128 + (((KS)*32 + hi*16) ^ swz)); \
                od1 = __builtin_amdgcn_mfma_f32_32x32x16_bf16(vf1, pu.v, od1, 0, 0, 0); \
            } while (0)

                __builtin_amdgcn_s_setprio(1);
                EXP_CHUNK(s0, rsc0);
                PV_STEP(s0, vl, 0, 0);
                PV_STEP(s0, vl, 1, 8);
                EXP_CHUNK(s1, rsc1);
                PV_STEP(s1, vl, 2, 0);
                PV_STEP(s1, vl, 3, 8);
                __builtin_amdgcn_s_setprio(0);
#undef PV_STEP
#undef EXP_CHUNK
                lsum += rsc0 + rsc1;
            }
            __syncthreads();
        }

        // ---- parity merge (p1 partial -> p0) via LDS scratch (reuse Klds[g]) ----
        char*  sod = reinterpret_cast<char*>(&Klds[g][0][0]);    // 8KB: od, lane*128
        float* sml = reinterpret_cast<float*>(&Klds[g][1][0]);   // m/lsum, lane*2
        const int lswz = (lane & 7) << 4;
        if (p == 1) {
            #pragma unroll
            for (int i = 0; i < 4; ++i) {
                *reinterpret_cast<f32x4*>(sod + lane*128 + ((i*16) ^ lswz)) =
                    (f32x4){od0[i*4+0], od0[i*4+1], od0[i*4+2], od0[i*4+3]};
                *reinterpret_cast<f32x4*>(sod + lane*128 + (((i+4)*16) ^ lswz)) =
                    (f32x4){od1[i*4+0], od1[i*4+1], od1[i*4+2], od1[i*4+3]};
            }
            sml[lane*2]     = m;
            sml[lane*2 + 1] = lsum;
        }
        __syncthreads();
        if (p == 0) {
            const float pm  = sml[lane*2];
            const float plv = sml[lane*2 + 1];
            const float mn = fmaxf(m, pm);
            const float a0 = __builtin_amdgcn_exp2f(m - mn);
            const float a1 = __builtin_amdgcn_exp2f(pm - mn);
            lsum = lsum*a0 + plv*a1;
            #pragma unroll
            for (int i = 0; i < 4; ++i) {
                f32x4 t0 = *reinterpret_cast<const f32x4*>(sod + lane*128 + ((i*16) ^ lswz));
                f32x4 t1 = *reinterpret_cast<const f32x4*>(sod + lane*128 + (((i+4)*16) ^ lswz));
                #pragma unroll
                for (int k = 0; k < 4; ++k) {
                    od0[i*4+k] = od0[i*4+k]*a0 + t0[k]*a1;
                    od1[i*4+k] = od1[i*4+k]*a0 + t1[k]*a1;
                }
            }
            // combine partner lsum across hi halves, normalize, write O
            {
                uint2v pr = __builtin_amdgcn_permlane32_swap(__float_as_uint(lsum), __float_as_uint(lsum), false, false);
                lsum = __uint_as_float(pr[0]) + __uint_as_float(pr[1]);
            }
            const float rls = 1.0f / lsum;
            const long obase = (long)((bh >> 3)*SEQ + q)*DM + (bh & 7)*DKH;
            #pragma unroll
            for (int rr = 0; rr < 4; ++rr) {
                ushort4 w0, w1;
                w0.x = f2bf(od0[rr*4+0]*rls); w0.y = f2bf(od0[rr*4+1]*rls);
                w0.z = f2bf(od0[rr*4+2]*rls); w0.w = f2bf(od0[rr*4+3]*rls);
                *reinterpret_cast<ushort4*>(Obf + obase + rr*8 + hi*4) = w0;
                w1.x = f2bf(od1[rr*4+0]*rls); w1.y = f2bf(od1[rr*4+1]*rls);
                w1.z = f2bf(od1[rr*4+2]*rls); w1.w = f2bf(od1[rr*4+3]*rls);
                *reinterpret_cast<ushort4*>(Obf + obase + 32 + rr*8 + hi*4) = w1;
            }
        }
        __syncthreads();   // protect scratch before next tile's staging
    }
}

extern "C" void kernel_launch(void* const* d_in, const int* in_sizes, int n_in,
                              void* d_out, int out_size, void* d_ws, size_t ws_size,
                              hipStream_t stream) {
    const float* x  = (const float*)d_in[0];
    const float* wq = (const float*)d_in[1];
    const float* wk = (const float*)d_in[2];
    const float* wv = (const float*)d_in[3];
    const float* bv = (const float*)d_in[4];
    const float* wo = (const float*)d_in[5];
    const float* bo = (const float*)d_in[6];
    float* out = (float*)d_out;

    unsigned short* ws = (unsigned short*)d_ws;
    unsigned short* Xbf  = ws;                       // 8192*512
    unsigned short* Wqkv = Xbf  + 4194304;           // 1536*512
    unsigned short* Wob  = Wqkv + 786432;            // 512*512
    unsigned short* Qh   = Wob  + 262144;            // [16][4096][64]
    unsigned short* Kh   = Qh   + 4194304;           // [16][4096][64]
    unsigned short* Vt   = Kh   + 4194304;           // [16][64][4096]
    unsigned short* Obf  = Vt   + 4194304;           // [8192][512]

    cast_kernel<<<5120, 256, 0, stream>>>(x, wq, wk, wv, wo, Xbf);

    dim3 g1(64, 12);
    gemm_bt<0><<<g1, 256, 0, stream>>>(Xbf, Wqkv, bv, Qh, Kh, Vt, nullptr);

    dim3 g2(16, 32);
    attn_kernel<<<g2, 256, 0, stream>>>(Qh, Kh, Vt, Obf);

    dim3 g3(64, 4);
    gemm_bt<1><<<g3, 256, 0, stream>>>(Obf, Wob, bo, nullptr, nullptr, nullptr, out);
}